// Round 1
// baseline (398.100 us; speedup 1.0000x reference)
//
#include <hip/hip_runtime.h>
#include <hip/hip_bf16.h>
#include <cstdint>
#include <type_traits>

// Problem constants (reference: N=8192, D=2048, M=512, E=4, SCALE=1)
#define N_TOK 8192
#define DDIM  2048
#define MDIM  512
#define NEXP  4

typedef __bf16 bf16x4 __attribute__((ext_vector_type(4)));
typedef __bf16 bf16x8 __attribute__((ext_vector_type(8)));
typedef float  f32x4  __attribute__((ext_vector_type(4)));

// ---------------------------------------------------------------------------
// Scratch in module device globals (fully rewritten every call).
// ---------------------------------------------------------------------------
__device__ int g_counts[NEXP];
__device__ int g_idx[NEXP * N_TOK];
__device__ __align__(16) __hip_bfloat16 g_H[(size_t)N_TOK * MDIM];          // 8 MB hidden acts
__device__ __align__(16) __hip_bfloat16 g_Xb[(size_t)N_TOK * DDIM];         // 32 MB x in bf16
__device__ __align__(16) __hip_bfloat16 g_W1b[(size_t)NEXP * MDIM * DDIM];  // 8 MB
__device__ __align__(16) __hip_bfloat16 g_W2b[(size_t)NEXP * DDIM * MDIM];  // 8 MB

__global__ void zero_counts_kernel() {
    if (threadIdx.x < NEXP) g_counts[threadIdx.x] = 0;
}

// ---------------------------------------------------------------------------
// Bucket tokens by expert — wave-aggregated atomics (verified in prior rounds).
// ---------------------------------------------------------------------------
__global__ void bucket_kernel(const void* __restrict__ domv) {
    const int i    = blockIdx.x * blockDim.x + threadIdx.x;
    const int lane = threadIdx.x & 63;

    // dtype detect: if the first 64 int64-views are all in [0,NEXP), it's int64
    const long long* d64 = (const long long*)domv;
    long long probe = d64[lane];
    bool mode64 = (__ballot(probe >= 0 && probe < NEXP) == ~0ull);

    const int e = mode64 ? (int)d64[i] : ((const int*)domv)[i];

#pragma unroll
    for (int ex = 0; ex < NEXP; ++ex) {
        unsigned long long m = __ballot(e == ex);
        if (m == 0) continue;                    // wave-uniform branch
        int cnt    = __popcll(m);
        int leader = __ffsll((long long)m) - 1;
        int base   = 0;
        if (lane == leader) base = atomicAdd(&g_counts[ex], cnt);
        base = __shfl(base, leader);
        if (e == ex) {
            int prefix = __popcll(m & ((1ull << lane) - 1ull));
            g_idx[ex * N_TOK + base + prefix] = i;
        }
    }
}

// ---------------------------------------------------------------------------
// fp32 -> bf16 pre-pass for x, W1, W2 (one launch, 3 grid-y segments).
// Memory-bound: ~144 MB total => ~23 us. Pays for itself by halving GEMM
// staging bytes and enabling global_load_lds (bf16-contiguous sources).
// ---------------------------------------------------------------------------
__global__ __launch_bounds__(256)
void cvt3_kernel(const float* __restrict__ x,
                 const float* __restrict__ w1,
                 const float* __restrict__ w2) {
    const float* src; __hip_bfloat16* dst; int n8;
    if (blockIdx.y == 0)      { src = x;  dst = g_Xb;  n8 = N_TOK * DDIM / 8; }
    else if (blockIdx.y == 1) { src = w1; dst = g_W1b; n8 = NEXP * MDIM * DDIM / 8; }
    else                      { src = w2; dst = g_W2b; n8 = NEXP * DDIM * MDIM / 8; }
    const int stride = gridDim.x * blockDim.x;
    for (int i = blockIdx.x * blockDim.x + threadIdx.x; i < n8; i += stride) {
        f32x4 a = ((const f32x4*)src)[2 * i];
        f32x4 b = ((const f32x4*)src)[2 * i + 1];
        bf16x8 r;
        r[0] = (__bf16)a[0]; r[1] = (__bf16)a[1]; r[2] = (__bf16)a[2]; r[3] = (__bf16)a[3];
        r[4] = (__bf16)b[0]; r[5] = (__bf16)b[1]; r[6] = (__bf16)b[2]; r[7] = (__bf16)b[3];
        ((bf16x8*)dst)[i] = r;
    }
}

// ---------------------------------------------------------------------------
// global -> LDS direct DMA, 16B per lane. LDS dest must be wave-uniform base
// (HW adds lane*16); global source IS per-lane (gather OK).
// ---------------------------------------------------------------------------
__device__ __forceinline__ void gl16(const __hip_bfloat16* g, __hip_bfloat16* l) {
    __builtin_amdgcn_global_load_lds(
        (const __attribute__((address_space(1))) void*)g,
        (__attribute__((address_space(3))) void*)l,
        16, 0, 0);
}

// ---------------------------------------------------------------------------
// Grouped NT GEMM over expert-gathered rows. BM=128, BK=64, 256 threads =
// 4 waves (2x2); wave computes 64 x (BN/2) via 4 x (BN/32) of 16x16x32 MFMA.
//   C[t,col] = act( sum_k A[t,k]*B[e,col,k] + bias[e,col] ) (+ resid[t,col])
//
// Staging: width-16 global_load_lds, double-buffered, 2-phase schedule:
//   stage(next) -> ds_read+MFMA(cur) -> __syncthreads (drains vmcnt) -> flip.
// Loads for tile t+1 are in flight across the whole MFMA phase of tile t.
//
// LDS XOR-swizzle (both-sides, rule #21): row stride is 128 B, so unswizzled
// ds_read_b128 is a 16-way bank conflict. Producer pre-swizzles the per-lane
// GLOBAL source column (slot ^= row&7, and row&7 == lane>>3 in our chunk map)
// while the LDS dest stays linear; consumer applies the same XOR on its read
// column (row&7 == lane&7 for fragment rows).
// ---------------------------------------------------------------------------
template <int BN, int KDIM, int NCOLS, bool RELU, bool RESID, typename TC>
__device__ __forceinline__ void gemm_core(const __hip_bfloat16* __restrict__ A,
                                          const __hip_bfloat16* __restrict__ B,
                                          const float* __restrict__ bias,
                                          const float* __restrict__ resid,
                                          TC* __restrict__ C) {
    constexpr int BM    = 128;
    constexpr int BK    = 64;
    constexpr int NACH  = 4;        // A chunks/thread: BM*BK*2B / 16B / 256
    constexpr int NBCH  = BN / 32;  // B chunks/thread
    constexpr int NJ    = BN / 32;  // col fragments per wave
    constexpr int NSTEP = KDIM / BK;

    const int e   = blockIdx.z;
    const int rt  = blockIdx.x;            // row (token-slot) tile [fast dim]
    const int ct  = blockIdx.y;            // col tile
    const int cnt = g_counts[e];
    if (rt * BM >= cnt) return;            // uniform across block

    __shared__ __align__(16) __hip_bfloat16 sA[2][BM * BK];
    __shared__ __align__(16) __hip_bfloat16 sB[2][BN * BK];
    __shared__ int sTok[BM];

    const int tid  = threadIdx.x;
    const int wave = tid >> 6;
    const int lane = tid & 63;

    if (tid < BM) {
        int slot = rt * BM + tid;
        sTok[tid] = g_idx[e * N_TOK + (slot < cnt ? slot : cnt - 1)];
    }
    __syncthreads();

    // --- staging source addresses ---
    // chunk q covers rows [q*32, q*32+32); lane l handles row q*32 + wave*8 + (l>>3),
    // 16B col-slot (l&7), which after swizzle fetches global slot (l&7)^(l>>3).
    const int srow = wave * 8 + (lane >> 3);
    const int ssl  = ((lane & 7) ^ (lane >> 3)) * 8;   // swizzled source col (elems)

    const __hip_bfloat16* gA[NACH];
#pragma unroll
    for (int q = 0; q < NACH; ++q)
        gA[q] = A + (size_t)sTok[q * 32 + srow] * KDIM + ssl;

    const size_t bbase = (size_t)e * NCOLS + (size_t)ct * BN;
    const __hip_bfloat16* gB[NBCH];
#pragma unroll
    for (int q = 0; q < NBCH; ++q)
        gB[q] = B + (bbase + (size_t)(q * 32 + srow)) * KDIM + ssl;

    auto stage = [&](int buf, int k0) {
#pragma unroll
        for (int q = 0; q < NACH; ++q)
            gl16(gA[q] + k0, &sA[buf][(q * 256 + wave * 64) * 8]);
#pragma unroll
        for (int q = 0; q < NBCH; ++q)
            gl16(gB[q] + k0, &sB[buf][(q * 256 + wave * 64) * 8]);
    };

    // --- fragment read addresses ---
    const int wm   = (wave >> 1) * 64;         // wave row offset in tile
    const int wn   = (wave & 1) * (BN / 2);    // wave col offset in tile
    const int frow = lane & 15;
    int cof[2];                                // swizzled k-col (elems) per k-slice
#pragma unroll
    for (int ks = 0; ks < 2; ++ks)
        cof[ks] = ((ks * 4 + (lane >> 4)) ^ (lane & 7)) * 8;

    f32x4 acc[4][NJ] = {};

    stage(0, 0);
    __syncthreads();                           // drains vmcnt(0): tile 0 visible

    int cur = 0;
    for (int t = 0; t < NSTEP; ++t) {
        if (t + 1 < NSTEP) stage(cur ^ 1, (t + 1) * BK);   // in flight across MFMA
        const __hip_bfloat16* pA = &sA[cur][0];
        const __hip_bfloat16* pB = &sB[cur][0];
#pragma unroll
        for (int ks = 0; ks < 2; ++ks) {
            bf16x8 af[4], bfr[NJ];
#pragma unroll
            for (int i = 0; i < 4; ++i)
                af[i] = *(const bf16x8*)&pA[(wm + i * 16 + frow) * BK + cof[ks]];
#pragma unroll
            for (int j = 0; j < NJ; ++j)
                bfr[j] = *(const bf16x8*)&pB[(wn + j * 16 + frow) * BK + cof[ks]];
#pragma unroll
            for (int i = 0; i < 4; ++i)
#pragma unroll
                for (int j = 0; j < NJ; ++j)
                    acc[i][j] = __builtin_amdgcn_mfma_f32_16x16x32_bf16(
                        af[i], bfr[j], acc[i][j], 0, 0, 0);
        }
        __syncthreads();                       // drains vmcnt(0) + lgkm + barrier
        cur ^= 1;
    }

    // epilogue: C/D layout col=lane&15, row=(lane>>4)*4+r  [m89/m91, verified]
    const int crow = (lane >> 4) * 4;
    const int ccol = lane & 15;
#pragma unroll
    for (int j = 0; j < NJ; ++j) {
        const int col = ct * BN + wn + j * 16 + ccol;
        const float bv = bias[(size_t)e * NCOLS + col];
#pragma unroll
        for (int i = 0; i < 4; ++i) {
            const int rl = wm + i * 16 + crow;
#pragma unroll
            for (int r = 0; r < 4; ++r) {
                const int slot = rt * BM + rl + r;
                if (slot < cnt) {
                    const int tk = sTok[rl + r];
                    float v = acc[i][j][r] + bv;
                    if (RELU)  v = fmaxf(v, 0.0f);
                    if (RESID) v += resid[(size_t)tk * NCOLS + col];
                    if constexpr (std::is_same<TC, float>::value)
                        C[(size_t)tk * NCOLS + col] = v;
                    else
                        C[(size_t)tk * NCOLS + col] = __float2bfloat16(v);
                }
            }
        }
    }
}

// GEMM1: H = relu(Xb @ W1b[e]^T + b1[e])   [K=2048, cols=512]
// BN=64 -> ct=8, ~16 active rt/expert -> ~512 active blocks (2/CU). LDS 48.5 KB.
__global__ __launch_bounds__(256)
void gemm1_kernel(const float* __restrict__ b1) {
    gemm_core<64, DDIM, MDIM, true, false, __hip_bfloat16>(g_Xb, g_W1b, b1, nullptr, g_H);
}

// GEMM2: out = x + H @ W2b[e]^T + b2[e]    [K=512, cols=2048]
// BN=128 -> ct=16, ~1024 active blocks. LDS 64.5 KB (2 blocks/CU).
__global__ __launch_bounds__(256)
void gemm2_kernel(const float* __restrict__ x,
                  const float* __restrict__ b2,
                  float* __restrict__ out) {
    gemm_core<128, MDIM, DDIM, false, true, float>(g_H, g_W2b, b2, x, out);
}

extern "C" void kernel_launch(void* const* d_in, const int* in_sizes, int n_in,
                              void* d_out, int out_size, void* d_ws, size_t ws_size,
                              hipStream_t stream) {
    const float* x  = (const float*)d_in[0];
    const void*  dm = d_in[1];
    const float* W1 = (const float*)d_in[2];
    const float* b1 = (const float*)d_in[3];
    const float* W2 = (const float*)d_in[4];
    const float* b2 = (const float*)d_in[5];
    float* out = (float*)d_out;

    zero_counts_kernel<<<1, 64, 0, stream>>>();
    bucket_kernel<<<N_TOK / 256, 256, 0, stream>>>(dm);
    cvt3_kernel<<<dim3(1024, 3), 256, 0, stream>>>(x, W1, W2);

    gemm1_kernel<<<dim3(N_TOK / 128, MDIM / 64, NEXP), 256, 0, stream>>>(b1);
    gemm2_kernel<<<dim3(N_TOK / 128, DDIM / 128, NEXP), 256, 0, stream>>>(x, b2, out);
}

// Round 2
// 303.132 us; speedup vs baseline: 1.3133x; 1.3133x over previous
//
#include <hip/hip_runtime.h>
#include <hip/hip_bf16.h>
#include <cstdint>
#include <type_traits>

// Problem constants (reference: N=8192, D=2048, M=512, E=4, SCALE=1)
#define N_TOK 8192
#define DDIM  2048
#define MDIM  512
#define NEXP  4

typedef __bf16 bf16x4 __attribute__((ext_vector_type(4)));
typedef __bf16 bf16x8 __attribute__((ext_vector_type(8)));
typedef float  f32x4  __attribute__((ext_vector_type(4)));

// ---------------------------------------------------------------------------
// Scratch in module device globals (fully rewritten every call).
// ---------------------------------------------------------------------------
__device__ int g_counts[NEXP];
__device__ int g_idx[NEXP * N_TOK];
__device__ __align__(16) __hip_bfloat16 g_H[(size_t)N_TOK * MDIM];          // 8 MB hidden acts
__device__ __align__(16) __hip_bfloat16 g_Xb[(size_t)N_TOK * DDIM];         // 32 MB x in bf16
__device__ __align__(16) __hip_bfloat16 g_W1b[(size_t)NEXP * MDIM * DDIM];  // 8 MB
__device__ __align__(16) __hip_bfloat16 g_W2b[(size_t)NEXP * DDIM * MDIM];  // 8 MB

__global__ void zero_counts_kernel() {
    if (threadIdx.x < NEXP) g_counts[threadIdx.x] = 0;
}

// ---------------------------------------------------------------------------
// Bucket tokens by expert — wave-aggregated atomics (verified in prior rounds).
// ---------------------------------------------------------------------------
__global__ void bucket_kernel(const void* __restrict__ domv) {
    const int i    = blockIdx.x * blockDim.x + threadIdx.x;
    const int lane = threadIdx.x & 63;

    // dtype detect: if the first 64 int64-views are all in [0,NEXP), it's int64
    const long long* d64 = (const long long*)domv;
    long long probe = d64[lane];
    bool mode64 = (__ballot(probe >= 0 && probe < NEXP) == ~0ull);

    const int e = mode64 ? (int)d64[i] : ((const int*)domv)[i];

#pragma unroll
    for (int ex = 0; ex < NEXP; ++ex) {
        unsigned long long m = __ballot(e == ex);
        if (m == 0) continue;                    // wave-uniform branch
        int cnt    = __popcll(m);
        int leader = __ffsll((long long)m) - 1;
        int base   = 0;
        if (lane == leader) base = atomicAdd(&g_counts[ex], cnt);
        base = __shfl(base, leader);
        if (e == ex) {
            int prefix = __popcll(m & ((1ull << lane) - 1ull));
            g_idx[ex * N_TOK + base + prefix] = i;
        }
    }
}

// ---------------------------------------------------------------------------
// fp32 -> bf16 pre-pass for x, W1, W2 (one launch, 3 grid-y segments).
// ---------------------------------------------------------------------------
__global__ __launch_bounds__(256)
void cvt3_kernel(const float* __restrict__ x,
                 const float* __restrict__ w1,
                 const float* __restrict__ w2) {
    const float* src; __hip_bfloat16* dst; int n8;
    if (blockIdx.y == 0)      { src = x;  dst = g_Xb;  n8 = N_TOK * DDIM / 8; }
    else if (blockIdx.y == 1) { src = w1; dst = g_W1b; n8 = NEXP * MDIM * DDIM / 8; }
    else                      { src = w2; dst = g_W2b; n8 = NEXP * DDIM * MDIM / 8; }
    const int stride = gridDim.x * blockDim.x;
    for (int i = blockIdx.x * blockDim.x + threadIdx.x; i < n8; i += stride) {
        f32x4 a = ((const f32x4*)src)[2 * i];
        f32x4 b = ((const f32x4*)src)[2 * i + 1];
        bf16x8 r;
        r[0] = (__bf16)a[0]; r[1] = (__bf16)a[1]; r[2] = (__bf16)a[2]; r[3] = (__bf16)a[3];
        r[4] = (__bf16)b[0]; r[5] = (__bf16)b[1]; r[6] = (__bf16)b[2]; r[7] = (__bf16)b[3];
        ((bf16x8*)dst)[i] = r;
    }
}

// ---------------------------------------------------------------------------
// global -> LDS direct DMA, 16B per lane. LDS dest must be wave-uniform base
// (HW adds lane*16); global source IS per-lane (gather OK).
// ---------------------------------------------------------------------------
__device__ __forceinline__ void gl16(const __hip_bfloat16* g, __hip_bfloat16* l) {
    __builtin_amdgcn_global_load_lds(
        (const __attribute__((address_space(1))) void*)g,
        (__attribute__((address_space(3))) void*)l,
        16, 0, 0);
}

// counted vmcnt wait (T4): immediate must be a literal -> constexpr dispatch
template <int N>
__device__ __forceinline__ void wait_vm() {
    if constexpr (N == 0)      asm volatile("s_waitcnt vmcnt(0)" ::: "memory");
    else if constexpr (N == 6) asm volatile("s_waitcnt vmcnt(6)" ::: "memory");
    else if constexpr (N == 8) asm volatile("s_waitcnt vmcnt(8)" ::: "memory");
}

// ---------------------------------------------------------------------------
// Grouped NT GEMM over expert-gathered rows. BM=128, BK=64, 256 threads =
// 4 waves (2x2); wave computes 64 x (BN/2) via 4 x (BN/32) of 16x16x32 MFMA.
//   C[t,col] = act( sum_k A[t,k]*B[e,col,k] + bias[e,col] ) (+ resid[t,col])
//
// Pipeline (T3+T4, 2-deep, counted vmcnt, RAW barriers — __syncthreads would
// emit s_waitcnt vmcnt(0) and drain the prefetch, which was the round-1 stall:
// MfmaUtil 4.6%, all pipes idle):
//   prologue: stage(tile0->buf0), stage(tile1->buf1)     [2*LPS in flight]
//   iter t:   s_waitcnt vmcnt(LPS)   -> tile t's loads done, t+1 still flying
//             s_barrier              -> all waves' tile-t loads done
//             ds_read + MFMA (buf t&1)
//             s_barrier              -> all waves done READING buf t&1
//             stage(tile t+2 -> buf t&1)
//   last iter: vmcnt(0) instead.
//
// MFMA operands are SWAPPED (mfma(b,a)): by C/D layout symmetry each lane
// then holds 4 consecutive C-columns of ONE token row -> f32x4 epilogue
// (vector bias/resid/store) instead of 4 scattered-row scalar accesses.
//
// LDS XOR-swizzle (both-sides, rule #21) unchanged from the passing version.
// ---------------------------------------------------------------------------
template <int BN, int KDIM, int NCOLS, bool RELU, bool RESID, typename TC>
__device__ __forceinline__ void gemm_core(const __hip_bfloat16* __restrict__ A,
                                          const __hip_bfloat16* __restrict__ B,
                                          const float* __restrict__ bias,
                                          const float* __restrict__ resid,
                                          TC* __restrict__ C) {
    constexpr int BM    = 128;
    constexpr int BK    = 64;
    constexpr int NACH  = 4;            // A chunks/thread
    constexpr int NBCH  = BN / 32;      // B chunks/thread
    constexpr int NJ    = BN / 32;      // col fragments per wave
    constexpr int NSTEP = KDIM / BK;
    constexpr int LPS   = NACH + NBCH;  // global_load_lds per wave per stage

    const int e   = blockIdx.z;
    const int rt  = blockIdx.x;            // row (token-slot) tile [fast dim]
    const int ct  = blockIdx.y;            // col tile
    const int cnt = g_counts[e];
    if (rt * BM >= cnt) return;            // uniform across block

    __shared__ __align__(16) __hip_bfloat16 sA[2][BM * BK];
    __shared__ __align__(16) __hip_bfloat16 sB[2][BN * BK];
    __shared__ int sTok[BM];

    const int tid  = threadIdx.x;
    const int wave = tid >> 6;
    const int lane = tid & 63;

    if (tid < BM) {
        int slot = rt * BM + tid;
        sTok[tid] = g_idx[e * N_TOK + (slot < cnt ? slot : cnt - 1)];
    }
    __syncthreads();

    // --- staging source addresses ---
    // chunk q covers rows [q*32, q*32+32); lane l handles row q*32+wave*8+(l>>3),
    // 16B col-slot (l&7)^(l>>3) (pre-swizzled global source, linear LDS dest).
    const int srow = wave * 8 + (lane >> 3);
    const int ssl  = ((lane & 7) ^ (lane >> 3)) * 8;   // swizzled source col (elems)

    const __hip_bfloat16* gA[NACH];
#pragma unroll
    for (int q = 0; q < NACH; ++q)
        gA[q] = A + (size_t)sTok[q * 32 + srow] * KDIM + ssl;

    const size_t bbase = (size_t)e * NCOLS + (size_t)ct * BN;
    const __hip_bfloat16* gB[NBCH];
#pragma unroll
    for (int q = 0; q < NBCH; ++q)
        gB[q] = B + (bbase + (size_t)(q * 32 + srow)) * KDIM + ssl;

    auto stage = [&](int buf, int k0) {
#pragma unroll
        for (int q = 0; q < NACH; ++q)
            gl16(gA[q] + k0, &sA[buf][(q * 256 + wave * 64) * 8]);
#pragma unroll
        for (int q = 0; q < NBCH; ++q)
            gl16(gB[q] + k0, &sB[buf][(q * 256 + wave * 64) * 8]);
    };

    // --- fragment read addresses ---
    const int wm   = (wave >> 1) * 64;         // wave row offset in tile
    const int wn   = (wave & 1) * (BN / 2);    // wave col offset in tile
    const int frow = lane & 15;
    int cof[2];                                // swizzled k-col (elems) per k-slice
#pragma unroll
    for (int ks = 0; ks < 2; ++ks)
        cof[ks] = ((ks * 4 + (lane >> 4)) ^ (lane & 7)) * 8;

    f32x4 acc[4][NJ] = {};

    auto compute = [&](int buf) {
        const __hip_bfloat16* pA = &sA[buf][0];
        const __hip_bfloat16* pB = &sB[buf][0];
#pragma unroll
        for (int ks = 0; ks < 2; ++ks) {
            bf16x8 af[4], bfr[NJ];
#pragma unroll
            for (int i = 0; i < 4; ++i)
                af[i] = *(const bf16x8*)&pA[(wm + i * 16 + frow) * BK + cof[ks]];
#pragma unroll
            for (int j = 0; j < NJ; ++j)
                bfr[j] = *(const bf16x8*)&pB[(wn + j * 16 + frow) * BK + cof[ks]];
#pragma unroll
            for (int i = 0; i < 4; ++i)
#pragma unroll
                for (int j = 0; j < NJ; ++j)   // SWAPPED operands: C^T layout
                    acc[i][j] = __builtin_amdgcn_mfma_f32_16x16x32_bf16(
                        bfr[j], af[i], acc[i][j], 0, 0, 0);
        }
    };

    stage(0, 0);
    stage(1, BK);

    int cur = 0;
    for (int t = 0; t < NSTEP - 1; ++t) {
        wait_vm<LPS>();                        // tile t done; t+1 stays in flight
        __builtin_amdgcn_s_barrier();
        __builtin_amdgcn_sched_barrier(0);
        compute(cur);
        asm volatile("" ::: "memory");         // pin ds_reads above the barrier
        __builtin_amdgcn_s_barrier();          // all waves done reading buf[cur]
        if (t + 2 < NSTEP) stage(cur, (t + 2) * BK);
        cur ^= 1;
    }
    wait_vm<0>();                              // drain last tile
    __builtin_amdgcn_s_barrier();
    __builtin_amdgcn_sched_barrier(0);
    compute(cur);

    // epilogue — swapped-operand C/D layout: for acc[i][j][r]:
    //   token row  = wm + i*16 + (lane&15)         (ONE row per lane)
    //   C column   = ct*BN + wn + j*16 + (lane>>4)*4 + r   (4 consecutive)
    const int lrow = lane & 15;
    const int lcol = (lane >> 4) * 4;
#pragma unroll
    for (int i = 0; i < 4; ++i) {
        const int rl   = wm + i * 16 + lrow;
        const int slot = rt * BM + rl;
        if (slot < cnt) {
            const int tk = sTok[rl];
#pragma unroll
            for (int j = 0; j < NJ; ++j) {
                const int col = ct * BN + wn + j * 16 + lcol;
                const f32x4 bv = *(const f32x4*)&bias[(size_t)e * NCOLS + col];
                f32x4 v = acc[i][j] + bv;
                if (RELU) {
#pragma unroll
                    for (int r = 0; r < 4; ++r) v[r] = fmaxf(v[r], 0.0f);
                }
                if (RESID) v += *(const f32x4*)&resid[(size_t)tk * NCOLS + col];
                if constexpr (std::is_same<TC, float>::value) {
                    *(f32x4*)&C[(size_t)tk * NCOLS + col] = v;
                } else {
                    bf16x4 h;
                    h[0] = (__bf16)v[0]; h[1] = (__bf16)v[1];
                    h[2] = (__bf16)v[2]; h[3] = (__bf16)v[3];
                    *(bf16x4*)&C[(size_t)tk * NCOLS + col] = h;
                }
            }
        }
    }
}

// GEMM1: H = relu(Xb @ W1b[e]^T + b1[e])   [K=2048, cols=512]  LPS=6
__global__ __launch_bounds__(256)
void gemm1_kernel(const float* __restrict__ b1) {
    gemm_core<64, DDIM, MDIM, true, false, __hip_bfloat16>(g_Xb, g_W1b, b1, nullptr, g_H);
}

// GEMM2: out = x + H @ W2b[e]^T + b2[e]    [K=512, cols=2048]  LPS=8
__global__ __launch_bounds__(256)
void gemm2_kernel(const float* __restrict__ x,
                  const float* __restrict__ b2,
                  float* __restrict__ out) {
    gemm_core<128, MDIM, DDIM, false, true, float>(g_H, g_W2b, b2, x, out);
}

extern "C" void kernel_launch(void* const* d_in, const int* in_sizes, int n_in,
                              void* d_out, int out_size, void* d_ws, size_t ws_size,
                              hipStream_t stream) {
    const float* x  = (const float*)d_in[0];
    const void*  dm = d_in[1];
    const float* W1 = (const float*)d_in[2];
    const float* b1 = (const float*)d_in[3];
    const float* W2 = (const float*)d_in[4];
    const float* b2 = (const float*)d_in[5];
    float* out = (float*)d_out;

    zero_counts_kernel<<<1, 64, 0, stream>>>();
    bucket_kernel<<<N_TOK / 256, 256, 0, stream>>>(dm);
    cvt3_kernel<<<dim3(1024, 3), 256, 0, stream>>>(x, W1, W2);

    gemm1_kernel<<<dim3(N_TOK / 128, MDIM / 64, NEXP), 256, 0, stream>>>(b1);
    gemm2_kernel<<<dim3(N_TOK / 128, DDIM / 128, NEXP), 256, 0, stream>>>(x, b2, out);
}